// Round 7
// baseline (168.243 us; speedup 1.0000x reference)
//
#include <hip/hip_runtime.h>

#define N_  2
#define C_  128
#define CR_ 64
#define H_  96
#define W_  96
#define L_  (H_*W_)     // 9216
#define QBLK 128        // q-rows per block = 2 waves x 64 rows
#define KVBLK 32
#define NQB (L_/QBLK)   // 72
#define SMAX 8
#define LOG2E 1.44269504088896f

typedef short bf16x8 __attribute__((ext_vector_type(8)));
typedef float f32x4  __attribute__((ext_vector_type(4)));

static __device__ __forceinline__ float exp2_fast(float x) {
    return __builtin_amdgcn_exp2f(x);
}

static __device__ __forceinline__ unsigned short f2bf(float f) {
    unsigned u = __builtin_bit_cast(unsigned, f);
    unsigned rounding = 0x7FFFu + ((u >> 16) & 1u);
    return (unsigned short)((u + rounding) >> 16);
}

static __device__ __forceinline__ unsigned cvt_pk_bf16(float lo, float hi) {
    unsigned r;
    asm("v_cvt_pk_bf16_f32 %0, %1, %2" : "=v"(r) : "v"(lo), "v"(hi));
    return r;
}

static __device__ __forceinline__ float bf2f(unsigned short s) {
    return __builtin_bit_cast(float, ((unsigned)s) << 16);
}

// K-row permutation for KVBLK=32: lds row rho <-> actual j = sigma(rho)
// rho bits [b4][b3b2][b1b0] -> j = [b3b2][b4][b1b0]
static __device__ __forceinline__ int sigma_(int r) {
    return ((r & 0x0C) << 1) | ((r & 0x10) >> 2) | (r & 3);
}

#define GLD16(G, Ld) __builtin_amdgcn_global_load_lds( \
    (const __attribute__((address_space(1))) void*)(G), \
    (__attribute__((address_space(3))) void*)(Ld), 16, 0, 0)

// ---------------------------------------------------------------------------
// Projection: q = prelu(W1 x + b1) * LOG2E, k = prelu(W2 x + b2), v = prelu(Wa x + ba)
// Outputs (bf16): q_t [N][L][CR], k_t [N][L][CR], v [N][C][L]. 32 positions/block.
// ---------------------------------------------------------------------------
__global__ __launch_bounds__(256) void proj_kernel(
    const float* __restrict__ x,
    const float* __restrict__ w1, const float* __restrict__ b1, const float* __restrict__ a1,
    const float* __restrict__ w2, const float* __restrict__ b2, const float* __restrict__ a2,
    const float* __restrict__ wa, const float* __restrict__ ba, const float* __restrict__ aa,
    unsigned short* __restrict__ qkv)
{
    __shared__ float xs[C_][32];
    const int blk = blockIdx.x;                // 0 .. N*L/32-1
    const int n   = blk / (L_/32);
    const int i0  = (blk % (L_/32)) * 32;
    const float* xb = x + (size_t)n * C_ * L_;

    #pragma unroll
    for (int k = 0; k < 4; k++) {
        int idx = threadIdx.x + k*256;
        int c = idx >> 3, j0 = (idx & 7) * 4;
        *reinterpret_cast<float4*>(&xs[c][j0]) =
            *reinterpret_cast<const float4*>(xb + (size_t)c * L_ + i0 + j0);
    }
    __syncthreads();

    const int t = threadIdx.x;
    const float* wrow;
    float bias, alpha, oscale;
    int o;
    if (t < 64)       { o = t;       wrow = w1 + o*C_; bias = b1[o]; alpha = a1[0]; oscale = LOG2E; }
    else if (t < 128) { o = t - 64;  wrow = w2 + o*C_; bias = b2[o]; alpha = a2[0]; oscale = 1.0f; }
    else              { o = t - 128; wrow = wa + o*C_; bias = ba[o]; alpha = aa[0]; oscale = 1.0f; }

    float acc[32];
    #pragma unroll
    for (int j = 0; j < 32; j++) acc[j] = bias;

    for (int c = 0; c < C_; c++) {
        float wv = wrow[c];
        #pragma unroll
        for (int j = 0; j < 32; j++) acc[j] += wv * xs[c][j];
    }

    unsigned short vals[32];
    #pragma unroll
    for (int j = 0; j < 32; j++) {
        float y = acc[j];
        y = (fmaxf(y, 0.0f) + alpha * fminf(y, 0.0f)) * oscale;
        vals[j] = f2bf(y);
    }

    unsigned short* q_t = qkv;
    unsigned short* k_t = qkv + (size_t)N_ * L_ * CR_;
    unsigned short* v   = qkv + (size_t)2 * N_ * L_ * CR_;

    if (t < 64) {
        unsigned short* d = q_t + (size_t)n * L_ * CR_;
        #pragma unroll
        for (int j = 0; j < 32; j++) d[(size_t)(i0 + j) * CR_ + o] = vals[j];
    } else if (t < 128) {
        unsigned short* d = k_t + (size_t)n * L_ * CR_;
        #pragma unroll
        for (int j = 0; j < 32; j++) d[(size_t)(i0 + j) * CR_ + o] = vals[j];
    } else {
        unsigned short* d = v + (size_t)n * C_ * L_ + (size_t)o * L_ + i0;
        #pragma unroll
        for (int g = 0; g < 4; g++) {
            union { unsigned short u[8]; int4 v4; } p;
            #pragma unroll
            for (int j = 0; j < 8; j++) p.u[j] = vals[g*8 + j];
            *reinterpret_cast<int4*>(d + g*8) = p.v4;
        }
    }
}

// ---------------------------------------------------------------------------
// Split-K flash attention. 2 waves x 64 q-rows (4 sub-tiles of 16), KVBLK=32.
// LDS/buffer 12KB: K [32 rho][64 c] (sigma-permuted rows, XOR-swizzled granules),
//                  V [64 rows][2c x 32 j] (2 c-rows per 128B, XOR-swizzled).
// Double buffered (24KB). 4 blocks/CU resident -> 4 independent barrier domains.
// ---------------------------------------------------------------------------
__global__ __launch_bounds__(128, 2) void attn_kernel(
    const unsigned short* __restrict__ qkv,
    unsigned short* __restrict__ o_part,  // [N][NQB][S][QBLK i][C c] bf16
    float* __restrict__ m_part,           // [N][NQB][S][QBLK]
    float* __restrict__ l_part,
    int S, int TILES_PER)
{
    __shared__ alignas(16) unsigned char kv_lds[2][12*1024];

    const unsigned short* q_t = qkv;
    const unsigned short* k_t = qkv + (size_t)N_ * L_ * CR_;
    const unsigned short* v   = qkv + (size_t)2 * N_ * L_ * CR_;

    const int blk  = blockIdx.x;
    const int n    = blk / (NQB * S);
    const int rem  = blk % (NQB * S);
    const int qbi  = rem / S;
    const int s    = rem % S;
    const int qb   = qbi * QBLK;
    const int tid  = threadIdx.x;
    const int wv   = tid >> 6;     // 0..1
    const int lane = tid & 63;
    const int lhi  = lane >> 4;    // 0..3
    const int llo  = lane & 15;    // q-row i within sub-tile

    const int jb_beg = s * TILES_PER * KVBLK;
    const int jb_end = min(L_, jb_beg + TILES_PER * KVBLK);

    const unsigned short* qtb = q_t + (size_t)n * L_ * CR_;
    const unsigned short* ktb = k_t + (size_t)n * L_ * CR_;
    const unsigned short* vb  = v   + (size_t)n * C_ * L_;

    // Q B-fragments for 4 sub-tiles (64 rows/wave)
    bf16x8 qf[4][2];
    #pragma unroll
    for (int st = 0; st < 4; st++) {
        int row = qb + wv * 64 + st * 16 + llo;
        #pragma unroll
        for (int ks = 0; ks < 2; ks++)
            qf[st][ks] = *reinterpret_cast<const bf16x8*>(qtb + (size_t)row * CR_ + ks*32 + lhi*8);
    }

    // staging sources (pre-swizzled global, linear LDS dest; 6 GLD16/thread)
    // K: granule id 0..255 -> rho=id>>3, gb=id&7, glin=gb^(rho&7)
    const unsigned short* ksrc[2];
    #pragma unroll
    for (int q = 0; q < 2; q++) {
        int id = q*128 + wv*64 + lane;
        int rho = id >> 3, gb = id & 7;
        int glin = gb ^ (rho & 7);
        ksrc[q] = ktb + (size_t)sigma_(rho) * CR_ + glin*8;
    }
    // V: granule vi 0..511 -> row=vi>>3, gb=vi&7, glin=gb^(row&7),
    //    c=row*2+(glin>>2), j8=(glin&3)*8
    const unsigned short* vsrc[4];
    #pragma unroll
    for (int q = 0; q < 4; q++) {
        int vi = q*128 + wv*64 + lane;
        int row = vi >> 3, gb = vi & 7;
        int glin = gb ^ (row & 7);
        int c  = row*2 + (glin >> 2);
        int j8 = (glin & 3) * 8;
        vsrc[q] = vb + (size_t)c * L_ + j8;
    }

    #define STAGE(b, jb_) do {                                          \
        size_t kof = (size_t)(jb_) * CR_;                               \
        GLD16(ksrc[0] + kof,  &kv_lds[b][(0*128 + wv*64)*16]);          \
        GLD16(ksrc[1] + kof,  &kv_lds[b][(1*128 + wv*64)*16]);          \
        GLD16(vsrc[0] + (jb_), &kv_lds[b][4096 + (0*128 + wv*64)*16]);  \
        GLD16(vsrc[1] + (jb_), &kv_lds[b][4096 + (1*128 + wv*64)*16]);  \
        GLD16(vsrc[2] + (jb_), &kv_lds[b][4096 + (2*128 + wv*64)*16]);  \
        GLD16(vsrc[3] + (jb_), &kv_lds[b][4096 + (3*128 + wv*64)*16]);  \
    } while (0)

    // per-lane LDS read address constants
    const int kg0 = ((0*4 + lhi) ^ (llo & 7)) * 16;   // ks=0 granule byte
    const int kg1 = ((1*4 + lhi) ^ (llo & 7)) * 16;   // ks=1
    const int vgb = ((((llo & 1) * 4 + lhi) ^ ((llo >> 1) & 7))) * 16;
    const int vrow_b = (llo >> 1) * 128;

    f32x4 o_acc[4][8];
    #pragma unroll
    for (int st = 0; st < 4; st++)
        #pragma unroll
        for (int ct = 0; ct < 8; ct++) o_acc[st][ct] = f32x4{0.f, 0.f, 0.f, 0.f};
    float m_run[4] = {-INFINITY, -INFINITY, -INFINITY, -INFINITY};
    float l_run[4] = {0.f, 0.f, 0.f, 0.f};

    int cur = 0;
    STAGE(0, jb_beg);
    __syncthreads();

    for (int jb = jb_beg; jb < jb_end; jb += KVBLK) {
        if (jb + KVBLK < jb_end) STAGE(cur ^ 1, jb + KVBLK);

        const unsigned char* kbuf = &kv_lds[cur][0];
        const unsigned char* vbuf = &kv_lds[cur][4096];

        // ---- S^T = K . Q^T : sacc[st][jt][r] = S(i=llo, lds-row jt*16+lhi*4+r) ----
        f32x4 sacc[4][2];
        #pragma unroll
        for (int st = 0; st < 4; st++) {
            sacc[st][0] = f32x4{0.f, 0.f, 0.f, 0.f};
            sacc[st][1] = f32x4{0.f, 0.f, 0.f, 0.f};
        }
        #pragma unroll
        for (int ks = 0; ks < 2; ks++) {
            const int kgb = ks ? kg1 : kg0;
            #pragma unroll
            for (int jt = 0; jt < 2; jt++) {
                bf16x8 kf = *reinterpret_cast<const bf16x8*>(
                    kbuf + jt*2048 + llo*128 + kgb);
                #pragma unroll
                for (int st = 0; st < 4; st++)
                    sacc[st][jt] = __builtin_amdgcn_mfma_f32_16x16x32_bf16(
                        kf, qf[st][ks], sacc[st][jt], 0, 0, 0);
            }
        }

        // ---- online softmax (base-2), per-lane row i=llo, reduce over lhi ----
        float tm[4];
        #pragma unroll
        for (int st = 0; st < 4; st++) {
            float m = fmaxf(fmaxf(fmaxf(sacc[st][0][0], sacc[st][0][1]),
                                  fmaxf(sacc[st][0][2], sacc[st][0][3])),
                            fmaxf(fmaxf(sacc[st][1][0], sacc[st][1][1]),
                                  fmaxf(sacc[st][1][2], sacc[st][1][3])));
            m = fmaxf(m, __shfl_xor(m, 16, 64));
            m = fmaxf(m, __shfl_xor(m, 32, 64));
            tm[st] = m;
        }
        bool ok = (tm[0] <= m_run[0] + 11.f) && (tm[1] <= m_run[1] + 11.f)
               && (tm[2] <= m_run[2] + 11.f) && (tm[3] <= m_run[3] + 11.f);
        if (!__all(ok)) {
            #pragma unroll
            for (int st = 0; st < 4; st++) {
                float mn = fmaxf(m_run[st], tm[st]);
                float sc = exp2_fast(m_run[st] - mn);
                #pragma unroll
                for (int ct = 0; ct < 8; ct++)
                    #pragma unroll
                    for (int r = 0; r < 4; r++) o_acc[st][ct][r] *= sc;
                l_run[st] *= sc;
                m_run[st] = mn;
            }
        }
        unsigned pk[4][4];
        #pragma unroll
        for (int st = 0; st < 4; st++) {
            float p0 = exp2_fast(sacc[st][0][0] - m_run[st]);
            float p1 = exp2_fast(sacc[st][0][1] - m_run[st]);
            float p2 = exp2_fast(sacc[st][0][2] - m_run[st]);
            float p3 = exp2_fast(sacc[st][0][3] - m_run[st]);
            float p4 = exp2_fast(sacc[st][1][0] - m_run[st]);
            float p5 = exp2_fast(sacc[st][1][1] - m_run[st]);
            float p6 = exp2_fast(sacc[st][1][2] - m_run[st]);
            float p7 = exp2_fast(sacc[st][1][3] - m_run[st]);
            float rs = ((p0 + p1) + (p2 + p3)) + ((p4 + p5) + (p6 + p7));
            pk[st][0] = cvt_pk_bf16(p0, p1);
            pk[st][1] = cvt_pk_bf16(p2, p3);
            pk[st][2] = cvt_pk_bf16(p4, p5);
            pk[st][3] = cvt_pk_bf16(p6, p7);
            rs += __shfl_xor(rs, 16, 64);
            rs += __shfl_xor(rs, 32, 64);
            l_run[st] += rs;
        }

        // ---- O^T += V^T . P^T : vf shared across 4 sub-tiles ----
        #pragma unroll
        for (int ct = 0; ct < 8; ct++) {
            bf16x8 vf = *reinterpret_cast<const bf16x8*>(
                vbuf + ct*1024 + vrow_b + vgb);
            #pragma unroll
            for (int st = 0; st < 4; st++) {
                bf16x8 pf = *reinterpret_cast<const bf16x8*>(&pk[st][0]);
                o_acc[st][ct] = __builtin_amdgcn_mfma_f32_16x16x32_bf16(
                    vf, pf, o_acc[st][ct], 0, 0, 0);
            }
        }

        __syncthreads();   // drains prefetch (implicit vmcnt(0)) + buffer handoff
        cur ^= 1;
    }

    // ---- write partials: o_acc[st][ct][r] = O[c=ct*16+lhi*4+r][i=wv*64+st*16+llo]
    unsigned short* ob = o_part + ((size_t)(n*NQB + qbi)*S + s) * (QBLK*C_);
    float* mb = m_part + ((size_t)(n*NQB + qbi)*S + s) * QBLK;
    float* lb = l_part + ((size_t)(n*NQB + qbi)*S + s) * QBLK;
    #pragma unroll
    for (int st = 0; st < 4; st++) {
        int i_loc = wv*64 + st*16 + llo;
        #pragma unroll
        for (int ct = 0; ct < 8; ct++) {
            int c0 = ct*16 + lhi*4;
            uint2 pkd;
            pkd.x = cvt_pk_bf16(o_acc[st][ct][0], o_acc[st][ct][1]);
            pkd.y = cvt_pk_bf16(o_acc[st][ct][2], o_acc[st][ct][3]);
            *reinterpret_cast<uint2*>(ob + (size_t)i_loc * C_ + c0) = pkd;
        }
        if (lhi == 0) {
            mb[i_loc] = m_run[st];
            lb[i_loc] = l_run[st];
        }
    }
    #undef STAGE
}

// ---------------------------------------------------------------------------
// Combine: out[n][c][i] = (sum_s O_s[i][c] * 2^(m_s-M)) / (sum_s l_s*2^(m_s-M)) + x
// ---------------------------------------------------------------------------
__global__ __launch_bounds__(256) void combine_kernel(
    const unsigned short* __restrict__ o_part,
    const float* __restrict__ m_part,
    const float* __restrict__ l_part,
    const float* __restrict__ x,
    float* __restrict__ out,
    int S)
{
    __shared__ float wls[SMAX][32];
    __shared__ float invl[32];

    const int blk  = blockIdx.x;
    const int part = blk & 3;
    const int qbi  = (blk >> 2) % NQB;
    const int n    = blk / (4 * NQB);
    const int tid  = threadIdx.x;
    const int i0   = part * 32;

    const size_t pbase = (size_t)(n*NQB + qbi) * S;

    if (tid < 32) {
        float m[SMAX], l[SMAX];
        float M = -INFINITY;
        for (int s = 0; s < S; s++) {
            m[s] = m_part[(pbase + s) * QBLK + i0 + tid];
            l[s] = l_part[(pbase + s) * QBLK + i0 + tid];
            M = fmaxf(M, m[s]);
        }
        float lt = 0.f;
        for (int s = 0; s < S; s++) {
            float w = exp2_fast(m[s] - M);
            wls[s][tid] = w;
            lt += w * l[s];
        }
        invl[tid] = 1.0f / lt;
    }
    __syncthreads();

    const int il = tid >> 3;           // 0..31
    const int cg = tid & 7;            // c-group: c = cg*16 .. +15

    float acc[16];
    #pragma unroll
    for (int k = 0; k < 16; k++) acc[k] = 0.f;

    for (int s = 0; s < S; s++) {
        const unsigned short* src = o_part + (pbase + s) * (QBLK*C_) + (size_t)(i0 + il) * C_ + cg*16;
        bf16x8 v0 = *reinterpret_cast<const bf16x8*>(src);
        bf16x8 v1 = *reinterpret_cast<const bf16x8*>(src + 8);
        float w = wls[s][il];
        #pragma unroll
        for (int k = 0; k < 8; k++) acc[k]     += w * bf2f((unsigned short)v0[k]);
        #pragma unroll
        for (int k = 0; k < 8; k++) acc[8 + k] += w * bf2f((unsigned short)v1[k]);
    }

    const float nv = invl[il];
    const int ig = qbi*QBLK + i0 + il;
    const float* xb = x   + (size_t)n * C_ * L_;
    float*       ob = out + (size_t)n * C_ * L_;
    #pragma unroll
    for (int k = 0; k < 16; k++) {
        int c = cg*16 + k;
        ob[(size_t)c * L_ + ig] = acc[k] * nv + xb[(size_t)c * L_ + ig];
    }
}

extern "C" void kernel_launch(void* const* d_in, const int* in_sizes, int n_in,
                              void* d_out, int out_size, void* d_ws, size_t ws_size,
                              hipStream_t stream) {
    const float* x  = (const float*)d_in[0];
    const float* w1 = (const float*)d_in[1];
    const float* b1 = (const float*)d_in[2];
    const float* a1 = (const float*)d_in[3];
    const float* w2 = (const float*)d_in[4];
    const float* b2 = (const float*)d_in[5];
    const float* a2 = (const float*)d_in[6];
    const float* wa = (const float*)d_in[7];
    const float* ba = (const float*)d_in[8];
    const float* aa = (const float*)d_in[9];
    float* out = (float*)d_out;

    unsigned short* qkv = (unsigned short*)d_ws;
    size_t qkv_bytes = ((size_t)2*N_*L_*CR_ + (size_t)N_*C_*L_) * 2;
    size_t off = (qkv_bytes + 255) & ~(size_t)255;

    // largest S<=8 fitting in ws (deterministic: ws_size fixed)
    int S = SMAX;
    while (S > 1) {
        size_t need = off + (size_t)N_*NQB*S * ((size_t)QBLK*C_*2 + 2*QBLK*4);
        if (need <= ws_size) break;
        S--;
    }
    unsigned short* o_part = (unsigned short*)((char*)d_ws + off);
    size_t o_elems = (size_t)N_*NQB*S*QBLK*C_;
    float* m_part = (float*)(o_part + o_elems);
    float* l_part = m_part + (size_t)N_*NQB*S*QBLK;
    int tiles_per = (L_/KVBLK + S - 1) / S;

    proj_kernel<<<N_ * (L_/32), 256, 0, stream>>>(x, w1, b1, a1, w2, b2, a2, wa, ba, aa, qkv);
    attn_kernel<<<N_ * NQB * S, 128, 0, stream>>>(qkv, o_part, m_part, l_part, S, tiles_per);
    combine_kernel<<<N_ * NQB * 4, 256, 0, stream>>>(o_part, m_part, l_part, x, out, S);
}

// Round 8
// 151.264 us; speedup vs baseline: 1.1122x; 1.1122x over previous
//
#include <hip/hip_runtime.h>

#define N_  2
#define C_  128
#define CR_ 64
#define H_  96
#define W_  96
#define L_  (H_*W_)     // 9216
#define QBLK 128        // q-rows per block = 4 waves x 32 rows
#define KVBLK 32
#define NQB (L_/QBLK)   // 72
#define SMAX 8
#define LOG2E 1.44269504088896f

typedef short bf16x8 __attribute__((ext_vector_type(8)));
typedef float f32x4  __attribute__((ext_vector_type(4)));

static __device__ __forceinline__ float exp2_fast(float x) {
    return __builtin_amdgcn_exp2f(x);
}

static __device__ __forceinline__ unsigned short f2bf(float f) {
    unsigned u = __builtin_bit_cast(unsigned, f);
    unsigned rounding = 0x7FFFu + ((u >> 16) & 1u);
    return (unsigned short)((u + rounding) >> 16);
}

static __device__ __forceinline__ unsigned cvt_pk_bf16(float lo, float hi) {
    unsigned r;
    asm("v_cvt_pk_bf16_f32 %0, %1, %2" : "=v"(r) : "v"(lo), "v"(hi));
    return r;
}

static __device__ __forceinline__ float bf2f(unsigned short s) {
    return __builtin_bit_cast(float, ((unsigned)s) << 16);
}

// K-row permutation (KVBLK=32): lds row rho holds actual j = sigma(rho)
// rho bits [b4][b3b2][b1b0] -> j = [b3b2][b4][b1b0]
// => lane (lhi,llo) after swapped QK^T holds exactly P[j=8*lhi+e][i=llo], e=0..7
static __device__ __forceinline__ int sigma_(int r) {
    return ((r & 0x0C) << 1) | ((r & 0x10) >> 2) | (r & 3);
}

#define GLD16(G, Ld) __builtin_amdgcn_global_load_lds( \
    (const __attribute__((address_space(1))) void*)(G), \
    (__attribute__((address_space(3))) void*)(Ld), 16, 0, 0)

// ---------------------------------------------------------------------------
// Projection: q = prelu(W1 x + b1) * LOG2E, k = prelu(W2 x + b2), v = prelu(Wa x + ba)
// Outputs (bf16): q_t [N][L][CR], k_t [N][L][CR], v [N][C][L]. 32 positions/block.
// ---------------------------------------------------------------------------
__global__ __launch_bounds__(256) void proj_kernel(
    const float* __restrict__ x,
    const float* __restrict__ w1, const float* __restrict__ b1, const float* __restrict__ a1,
    const float* __restrict__ w2, const float* __restrict__ b2, const float* __restrict__ a2,
    const float* __restrict__ wa, const float* __restrict__ ba, const float* __restrict__ aa,
    unsigned short* __restrict__ qkv)
{
    __shared__ float xs[C_][32];
    const int blk = blockIdx.x;                // 0 .. N*L/32-1
    const int n   = blk / (L_/32);
    const int i0  = (blk % (L_/32)) * 32;
    const float* xb = x + (size_t)n * C_ * L_;

    #pragma unroll
    for (int k = 0; k < 4; k++) {
        int idx = threadIdx.x + k*256;
        int c = idx >> 3, j0 = (idx & 7) * 4;
        *reinterpret_cast<float4*>(&xs[c][j0]) =
            *reinterpret_cast<const float4*>(xb + (size_t)c * L_ + i0 + j0);
    }
    __syncthreads();

    const int t = threadIdx.x;
    const float* wrow;
    float bias, alpha, oscale;
    int o;
    if (t < 64)       { o = t;       wrow = w1 + o*C_; bias = b1[o]; alpha = a1[0]; oscale = LOG2E; }
    else if (t < 128) { o = t - 64;  wrow = w2 + o*C_; bias = b2[o]; alpha = a2[0]; oscale = 1.0f; }
    else              { o = t - 128; wrow = wa + o*C_; bias = ba[o]; alpha = aa[0]; oscale = 1.0f; }

    float acc[32];
    #pragma unroll
    for (int j = 0; j < 32; j++) acc[j] = bias;

    for (int c = 0; c < C_; c++) {
        float wv = wrow[c];
        #pragma unroll
        for (int j = 0; j < 32; j++) acc[j] += wv * xs[c][j];
    }

    unsigned short vals[32];
    #pragma unroll
    for (int j = 0; j < 32; j++) {
        float y = acc[j];
        y = (fmaxf(y, 0.0f) + alpha * fminf(y, 0.0f)) * oscale;
        vals[j] = f2bf(y);
    }

    unsigned short* q_t = qkv;
    unsigned short* k_t = qkv + (size_t)N_ * L_ * CR_;
    unsigned short* v   = qkv + (size_t)2 * N_ * L_ * CR_;

    if (t < 64) {
        unsigned short* d = q_t + (size_t)n * L_ * CR_;
        #pragma unroll
        for (int j = 0; j < 32; j++) d[(size_t)(i0 + j) * CR_ + o] = vals[j];
    } else if (t < 128) {
        unsigned short* d = k_t + (size_t)n * L_ * CR_;
        #pragma unroll
        for (int j = 0; j < 32; j++) d[(size_t)(i0 + j) * CR_ + o] = vals[j];
    } else {
        unsigned short* d = v + (size_t)n * C_ * L_ + (size_t)o * L_ + i0;
        #pragma unroll
        for (int g = 0; g < 4; g++) {
            union { unsigned short u[8]; int4 v4; } p;
            #pragma unroll
            for (int j = 0; j < 8; j++) p.u[j] = vals[g*8 + j];
            *reinterpret_cast<int4*>(d + g*8) = p.v4;
        }
    }
}

// ---------------------------------------------------------------------------
// Split-K flash attention. 4 waves x 32 q-rows (2 sub-tiles of 16), KVBLK=32.
// LDS/buffer 12KB: K [32 rho][64 c] (sigma-permuted rows, XOR-swizzled granules),
//                  V [64 rows][2c x 32 j] (2 c-rows per 128B row, XOR-swizzled).
// Double buffered (24KB total) -> 3 blocks/CU (register-capped), 12 waves/CU.
// ---------------------------------------------------------------------------
__global__ __launch_bounds__(256, 3) void attn_kernel(
    const unsigned short* __restrict__ qkv,
    unsigned short* __restrict__ o_part,  // [N][NQB][S][QBLK i][C c] bf16
    float* __restrict__ m_part,           // [N][NQB][S][QBLK]
    float* __restrict__ l_part,
    int S, int TILES_PER)
{
    __shared__ alignas(16) unsigned char kv_lds[2][12*1024];

    const unsigned short* q_t = qkv;
    const unsigned short* k_t = qkv + (size_t)N_ * L_ * CR_;
    const unsigned short* v   = qkv + (size_t)2 * N_ * L_ * CR_;

    const int blk  = blockIdx.x;
    const int n    = blk / (NQB * S);
    const int rem  = blk % (NQB * S);
    const int qbi  = rem / S;
    const int s    = rem % S;
    const int qb   = qbi * QBLK;
    const int tid  = threadIdx.x;
    const int wave = tid >> 6;     // 0..3
    const int lane = tid & 63;
    const int lhi  = lane >> 4;    // 0..3
    const int llo  = lane & 15;    // q-row i within sub-tile

    const int jb_beg = s * TILES_PER * KVBLK;
    const int jb_end = min(L_, jb_beg + TILES_PER * KVBLK);

    const unsigned short* qtb = q_t + (size_t)n * L_ * CR_;
    const unsigned short* ktb = k_t + (size_t)n * L_ * CR_;
    const unsigned short* vb  = v   + (size_t)n * C_ * L_;

    // Q B-fragments (col=llo -> q-row, k=lhi*8+e -> c), 2 sub-tiles of 16 rows
    bf16x8 qf[2][2];
    #pragma unroll
    for (int st = 0; st < 2; st++) {
        int row = qb + wave * 32 + st * 16 + llo;
        #pragma unroll
        for (int ks = 0; ks < 2; ks++)
            qf[st][ks] = *reinterpret_cast<const bf16x8*>(qtb + (size_t)row * CR_ + ks*32 + lhi*8);
    }

    // staging sources (pre-swizzled global, linear LDS dest; 3 GLD16/thread)
    // K: 4KB = 256 granules, 1/thread: rho=tid>>3, gb=tid&7, glin=gb^(rho&7)
    const unsigned short* ksrc;
    {
        int rho = tid >> 3, gb = tid & 7;
        int glin = gb ^ (rho & 7);
        ksrc = ktb + (size_t)sigma_(rho) * CR_ + glin*8;
    }
    // V: 8KB = 512 granules, 2/thread: row=vi>>3 (0..63), gb=vi&7, glin=gb^(row&7),
    //    c=row*2+(glin>>2), j8=(glin&3)*8
    const unsigned short* vsrc[2];
    #pragma unroll
    for (int q = 0; q < 2; q++) {
        int vi = q*256 + tid;
        int row = vi >> 3, gb = vi & 7;
        int glin = gb ^ (row & 7);
        int c  = row*2 + (glin >> 2);
        int j8 = (glin & 3) * 8;
        vsrc[q] = vb + (size_t)c * L_ + j8;
    }

    #define STAGE(b, jb_) do {                                           \
        GLD16(ksrc + (size_t)(jb_) * CR_, &kv_lds[b][wave*1024]);        \
        GLD16(vsrc[0] + (jb_), &kv_lds[b][4096 + wave*1024]);            \
        GLD16(vsrc[1] + (jb_), &kv_lds[b][8192 + wave*1024]);            \
    } while (0)

    // per-lane LDS read constants
    const int kg0 = ((0*4 + lhi) ^ (llo & 7)) * 16;   // ks=0 K granule byte
    const int kg1 = ((1*4 + lhi) ^ (llo & 7)) * 16;   // ks=1
    const int vgb = (((llo & 1) * 4 + lhi) ^ ((llo >> 1) & 7)) * 16;
    const int vrow_b = (llo >> 1) * 128;

    f32x4 o_acc[2][8];
    #pragma unroll
    for (int st = 0; st < 2; st++)
        #pragma unroll
        for (int ct = 0; ct < 8; ct++) o_acc[st][ct] = f32x4{0.f, 0.f, 0.f, 0.f};
    float m_run[2] = {-INFINITY, -INFINITY};
    float l_run[2] = {0.f, 0.f};

    int cur = 0;
    STAGE(0, jb_beg);
    __syncthreads();

    for (int jb = jb_beg; jb < jb_end; jb += KVBLK) {
        if (jb + KVBLK < jb_end) STAGE(cur ^ 1, jb + KVBLK);

        const unsigned char* kbuf = &kv_lds[cur][0];
        const unsigned char* vbuf = &kv_lds[cur][4096];

        // ---- S^T = K . Q^T : sacc[st][jt][r] = S^T(lds-row jt*16+lhi*4+r, i=llo) ----
        f32x4 sacc[2][2];
        #pragma unroll
        for (int st = 0; st < 2; st++) {
            sacc[st][0] = f32x4{0.f, 0.f, 0.f, 0.f};
            sacc[st][1] = f32x4{0.f, 0.f, 0.f, 0.f};
        }
        __builtin_amdgcn_s_setprio(1);
        #pragma unroll
        for (int ks = 0; ks < 2; ks++) {
            const int kgb = ks ? kg1 : kg0;
            #pragma unroll
            for (int jt = 0; jt < 2; jt++) {
                bf16x8 kf = *reinterpret_cast<const bf16x8*>(
                    kbuf + jt*2048 + llo*128 + kgb);
                #pragma unroll
                for (int st = 0; st < 2; st++)
                    sacc[st][jt] = __builtin_amdgcn_mfma_f32_16x16x32_bf16(
                        kf, qf[st][ks], sacc[st][jt], 0, 0, 0);
            }
        }
        __builtin_amdgcn_s_setprio(0);

        // ---- online softmax (base-2), per-lane row i=llo, reduce over lhi ----
        float tm[2];
        #pragma unroll
        for (int st = 0; st < 2; st++) {
            float m = fmaxf(fmaxf(fmaxf(sacc[st][0][0], sacc[st][0][1]),
                                  fmaxf(sacc[st][0][2], sacc[st][0][3])),
                            fmaxf(fmaxf(sacc[st][1][0], sacc[st][1][1]),
                                  fmaxf(sacc[st][1][2], sacc[st][1][3])));
            m = fmaxf(m, __shfl_xor(m, 16, 64));
            m = fmaxf(m, __shfl_xor(m, 32, 64));
            tm[st] = m;
        }
        if (!__all(tm[0] <= m_run[0] + 11.f && tm[1] <= m_run[1] + 11.f)) {
            #pragma unroll
            for (int st = 0; st < 2; st++) {
                float mn = fmaxf(m_run[st], tm[st]);
                float sc = exp2_fast(m_run[st] - mn);
                #pragma unroll
                for (int ct = 0; ct < 8; ct++)
                    #pragma unroll
                    for (int r = 0; r < 4; r++) o_acc[st][ct][r] *= sc;
                l_run[st] *= sc;
                m_run[st] = mn;
            }
        }
        unsigned pk[2][4];
        #pragma unroll
        for (int st = 0; st < 2; st++) {
            float p0 = exp2_fast(sacc[st][0][0] - m_run[st]);
            float p1 = exp2_fast(sacc[st][0][1] - m_run[st]);
            float p2 = exp2_fast(sacc[st][0][2] - m_run[st]);
            float p3 = exp2_fast(sacc[st][0][3] - m_run[st]);
            float p4 = exp2_fast(sacc[st][1][0] - m_run[st]);
            float p5 = exp2_fast(sacc[st][1][1] - m_run[st]);
            float p6 = exp2_fast(sacc[st][1][2] - m_run[st]);
            float p7 = exp2_fast(sacc[st][1][3] - m_run[st]);
            float rs = ((p0 + p1) + (p2 + p3)) + ((p4 + p5) + (p6 + p7));
            pk[st][0] = cvt_pk_bf16(p0, p1);
            pk[st][1] = cvt_pk_bf16(p2, p3);
            pk[st][2] = cvt_pk_bf16(p4, p5);
            pk[st][3] = cvt_pk_bf16(p6, p7);
            rs += __shfl_xor(rs, 16, 64);
            rs += __shfl_xor(rs, 32, 64);
            l_run[st] += rs;
        }

        // ---- O^T += V^T . P^T : vf shared across both sub-tiles ----
        __builtin_amdgcn_s_setprio(1);
        #pragma unroll
        for (int ct = 0; ct < 8; ct++) {
            bf16x8 vf = *reinterpret_cast<const bf16x8*>(
                vbuf + ct*1024 + vrow_b + vgb);
            #pragma unroll
            for (int st = 0; st < 2; st++) {
                bf16x8 pf = *reinterpret_cast<const bf16x8*>(&pk[st][0]);
                o_acc[st][ct] = __builtin_amdgcn_mfma_f32_16x16x32_bf16(
                    vf, pf, o_acc[st][ct], 0, 0, 0);
            }
        }
        __builtin_amdgcn_s_setprio(0);

        __syncthreads();   // drains prefetch (implicit vmcnt(0)) + buffer handoff
        cur ^= 1;
    }

    // ---- write partials: o_acc[st][ct][r] = O[c=ct*16+lhi*4+r][i=wave*32+st*16+llo]
    unsigned short* ob = o_part + ((size_t)(n*NQB + qbi)*S + s) * (QBLK*C_);
    float* mb = m_part + ((size_t)(n*NQB + qbi)*S + s) * QBLK;
    float* lb = l_part + ((size_t)(n*NQB + qbi)*S + s) * QBLK;
    #pragma unroll
    for (int st = 0; st < 2; st++) {
        int i_loc = wave*32 + st*16 + llo;
        #pragma unroll
        for (int ct = 0; ct < 8; ct++) {
            int c0 = ct*16 + lhi*4;
            uint2 pkd;
            pkd.x = cvt_pk_bf16(o_acc[st][ct][0], o_acc[st][ct][1]);
            pkd.y = cvt_pk_bf16(o_acc[st][ct][2], o_acc[st][ct][3]);
            *reinterpret_cast<uint2*>(ob + (size_t)i_loc * C_ + c0) = pkd;
        }
        if (lhi == 0) {
            mb[i_loc] = m_run[st];
            lb[i_loc] = l_run[st];
        }
    }
    #undef STAGE
}

// ---------------------------------------------------------------------------
// Combine: out[n][c][i] = (sum_s O_s[i][c] * 2^(m_s-M)) / (sum_s l_s*2^(m_s-M)) + x
// ---------------------------------------------------------------------------
__global__ __launch_bounds__(256) void combine_kernel(
    const unsigned short* __restrict__ o_part,
    const float* __restrict__ m_part,
    const float* __restrict__ l_part,
    const float* __restrict__ x,
    float* __restrict__ out,
    int S)
{
    __shared__ float wls[SMAX][32];
    __shared__ float invl[32];

    const int blk  = blockIdx.x;
    const int part = blk & 3;
    const int qbi  = (blk >> 2) % NQB;
    const int n    = blk / (4 * NQB);
    const int tid  = threadIdx.x;
    const int i0   = part * 32;

    const size_t pbase = (size_t)(n*NQB + qbi) * S;

    if (tid < 32) {
        float m[SMAX], l[SMAX];
        float M = -INFINITY;
        for (int s = 0; s < S; s++) {
            m[s] = m_part[(pbase + s) * QBLK + i0 + tid];
            l[s] = l_part[(pbase + s) * QBLK + i0 + tid];
            M = fmaxf(M, m[s]);
        }
        float lt = 0.f;
        for (int s = 0; s < S; s++) {
            float w = exp2_fast(m[s] - M);
            wls[s][tid] = w;
            lt += w * l[s];
        }
        invl[tid] = 1.0f / lt;
    }
    __syncthreads();

    const int il = tid >> 3;           // 0..31
    const int cg = tid & 7;            // c-group: c = cg*16 .. +15

    float acc[16];
    #pragma unroll
    for (int k = 0; k < 16; k++) acc[k] = 0.f;

    for (int s = 0; s < S; s++) {
        const unsigned short* src = o_part + (pbase + s) * (QBLK*C_) + (size_t)(i0 + il) * C_ + cg*16;
        bf16x8 v0 = *reinterpret_cast<const bf16x8*>(src);
        bf16x8 v1 = *reinterpret_cast<const bf16x8*>(src + 8);
        float w = wls[s][il];
        #pragma unroll
        for (int k = 0; k < 8; k++) acc[k]     += w * bf2f((unsigned short)v0[k]);
        #pragma unroll
        for (int k = 0; k < 8; k++) acc[8 + k] += w * bf2f((unsigned short)v1[k]);
    }

    const float nv = invl[il];
    const int ig = qbi*QBLK + i0 + il;
    const float* xb = x   + (size_t)n * C_ * L_;
    float*       ob = out + (size_t)n * C_ * L_;
    #pragma unroll
    for (int k = 0; k < 16; k++) {
        int c = cg*16 + k;
        ob[(size_t)c * L_ + ig] = acc[k] * nv + xb[(size_t)c * L_ + ig];
    }
}

extern "C" void kernel_launch(void* const* d_in, const int* in_sizes, int n_in,
                              void* d_out, int out_size, void* d_ws, size_t ws_size,
                              hipStream_t stream) {
    const float* x  = (const float*)d_in[0];
    const float* w1 = (const float*)d_in[1];
    const float* b1 = (const float*)d_in[2];
    const float* a1 = (const float*)d_in[3];
    const float* w2 = (const float*)d_in[4];
    const float* b2 = (const float*)d_in[5];
    const float* a2 = (const float*)d_in[6];
    const float* wa = (const float*)d_in[7];
    const float* ba = (const float*)d_in[8];
    const float* aa = (const float*)d_in[9];
    float* out = (float*)d_out;

    unsigned short* qkv = (unsigned short*)d_ws;
    size_t qkv_bytes = ((size_t)2*N_*L_*CR_ + (size_t)N_*C_*L_) * 2;
    size_t off = (qkv_bytes + 255) & ~(size_t)255;

    // largest S<=8 fitting in ws (deterministic: ws_size fixed)
    int S = SMAX;
    while (S > 1) {
        size_t need = off + (size_t)N_*NQB*S * ((size_t)QBLK*C_*2 + 2*QBLK*4);
        if (need <= ws_size) break;
        S--;
    }
    unsigned short* o_part = (unsigned short*)((char*)d_ws + off);
    size_t o_elems = (size_t)N_*NQB*S*QBLK*C_;
    float* m_part = (float*)(o_part + o_elems);
    float* l_part = m_part + (size_t)N_*NQB*S*QBLK;
    int tiles_per = (L_/KVBLK + S - 1) / S;

    proj_kernel<<<N_ * (L_/32), 256, 0, stream>>>(x, w1, b1, a1, w2, b2, a2, wa, ba, aa, qkv);
    attn_kernel<<<N_ * NQB * S, 256, 0, stream>>>(qkv, o_part, m_part, l_part, S, tiles_per);
    combine_kernel<<<N_ * NQB * 4, 256, 0, stream>>>(o_part, m_part, l_part, x, out, S);
}

// Round 9
// 127.569 us; speedup vs baseline: 1.3188x; 1.1857x over previous
//
#include <hip/hip_runtime.h>

#define N_  2
#define C_  128
#define CR_ 64
#define H_  96
#define W_  96
#define L_  (H_*W_)     // 9216
#define QBLK 128        // q-rows per block = 4 waves x 32 rows
#define KVBLK 64
#define NQB (L_/QBLK)   // 72
#define SMAX 8
#define LOG2E 1.44269504088896f

typedef short bf16x8 __attribute__((ext_vector_type(8)));
typedef float f32x4  __attribute__((ext_vector_type(4)));

static __device__ __forceinline__ float exp2_fast(float x) {
    return __builtin_amdgcn_exp2f(x);
}

static __device__ __forceinline__ unsigned short f2bf(float f) {
    unsigned u = __builtin_bit_cast(unsigned, f);
    unsigned rounding = 0x7FFFu + ((u >> 16) & 1u);
    return (unsigned short)((u + rounding) >> 16);
}

static __device__ __forceinline__ unsigned cvt_pk_bf16(float lo, float hi) {
    unsigned r;
    asm("v_cvt_pk_bf16_f32 %0, %1, %2" : "=v"(r) : "v"(lo), "v"(hi));
    return r;
}

static __device__ __forceinline__ float bf2f(unsigned short s) {
    return __builtin_bit_cast(float, ((unsigned)s) << 16);
}

// K-row permutation (KVBLK=64): lds row rho holds actual j = sigma(rho)
// rho bits [ks][e4][lhi1][lhi0][r1][r0] -> [ks][lhi1][lhi0][e4][r1][r0]
static __device__ __forceinline__ int sigma_(int r) {
    return (r & 0x23) | ((r & 0x0C) << 1) | ((r & 0x10) >> 2);
}

#define GLD16(G, Ld) __builtin_amdgcn_global_load_lds( \
    (const __attribute__((address_space(1))) void*)(G), \
    (__attribute__((address_space(3))) void*)(Ld), 16, 0, 0)

// ---------------------------------------------------------------------------
// Projection: q = prelu(W1 x + b1) * LOG2E, k = prelu(W2 x + b2), v = prelu(Wa x + ba)
// Outputs (bf16): q_t [N][L][CR], k_t [N][L][CR], v [N][C][L]. 32 positions/block.
// ---------------------------------------------------------------------------
__global__ __launch_bounds__(256) void proj_kernel(
    const float* __restrict__ x,
    const float* __restrict__ w1, const float* __restrict__ b1, const float* __restrict__ a1,
    const float* __restrict__ w2, const float* __restrict__ b2, const float* __restrict__ a2,
    const float* __restrict__ wa, const float* __restrict__ ba, const float* __restrict__ aa,
    unsigned short* __restrict__ qkv)
{
    __shared__ float xs[C_][32];
    const int blk = blockIdx.x;                // 0 .. N*L/32-1
    const int n   = blk / (L_/32);
    const int i0  = (blk % (L_/32)) * 32;
    const float* xb = x + (size_t)n * C_ * L_;

    #pragma unroll
    for (int k = 0; k < 4; k++) {
        int idx = threadIdx.x + k*256;
        int c = idx >> 3, j0 = (idx & 7) * 4;
        *reinterpret_cast<float4*>(&xs[c][j0]) =
            *reinterpret_cast<const float4*>(xb + (size_t)c * L_ + i0 + j0);
    }
    __syncthreads();

    const int t = threadIdx.x;
    const float* wrow;
    float bias, alpha, oscale;
    int o;
    if (t < 64)       { o = t;       wrow = w1 + o*C_; bias = b1[o]; alpha = a1[0]; oscale = LOG2E; }
    else if (t < 128) { o = t - 64;  wrow = w2 + o*C_; bias = b2[o]; alpha = a2[0]; oscale = 1.0f; }
    else              { o = t - 128; wrow = wa + o*C_; bias = ba[o]; alpha = aa[0]; oscale = 1.0f; }

    float acc[32];
    #pragma unroll
    for (int j = 0; j < 32; j++) acc[j] = bias;

    for (int c = 0; c < C_; c++) {
        float wv = wrow[c];
        #pragma unroll
        for (int j = 0; j < 32; j++) acc[j] += wv * xs[c][j];
    }

    unsigned short vals[32];
    #pragma unroll
    for (int j = 0; j < 32; j++) {
        float y = acc[j];
        y = (fmaxf(y, 0.0f) + alpha * fminf(y, 0.0f)) * oscale;
        vals[j] = f2bf(y);
    }

    unsigned short* q_t = qkv;
    unsigned short* k_t = qkv + (size_t)N_ * L_ * CR_;
    unsigned short* v   = qkv + (size_t)2 * N_ * L_ * CR_;

    if (t < 64) {
        unsigned short* d = q_t + (size_t)n * L_ * CR_;
        #pragma unroll
        for (int j = 0; j < 32; j++) d[(size_t)(i0 + j) * CR_ + o] = vals[j];
    } else if (t < 128) {
        unsigned short* d = k_t + (size_t)n * L_ * CR_;
        #pragma unroll
        for (int j = 0; j < 32; j++) d[(size_t)(i0 + j) * CR_ + o] = vals[j];
    } else {
        unsigned short* d = v + (size_t)n * C_ * L_ + (size_t)o * L_ + i0;
        #pragma unroll
        for (int g = 0; g < 4; g++) {
            union { unsigned short u[8]; int4 v4; } p;
            #pragma unroll
            for (int j = 0; j < 8; j++) p.u[j] = vals[g*8 + j];
            *reinterpret_cast<int4*>(d + g*8) = p.v4;
        }
    }
}

// ---------------------------------------------------------------------------
// Split-K flash attention, FIXED-SHIFT softmax (m == 0; combine renormalizes).
// 4 waves x 32 q-rows (2 sub-tiles of 16), KVBLK=64.
// LDS per buffer 24KB: K [64 rho][64 c] (sigma-permuted, XOR-swizzled),
//                      V [128 c][64 j] (XOR-swizzled). Double buffered.
// P = exp2(S) directly; per-lane l accumulates, cross-lane reduced ONCE at end.
// ---------------------------------------------------------------------------
__global__ __launch_bounds__(256, 3) void attn_kernel(
    const unsigned short* __restrict__ qkv,
    unsigned short* __restrict__ o_part,  // [N][NQB][S][QBLK i][C c] bf16
    float* __restrict__ l_part,           // [N][NQB][S][QBLK]
    int S, int TILES_PER)
{
    __shared__ alignas(16) unsigned char kv_lds[2][24*1024];

    const unsigned short* q_t = qkv;
    const unsigned short* k_t = qkv + (size_t)N_ * L_ * CR_;
    const unsigned short* v   = qkv + (size_t)2 * N_ * L_ * CR_;

    const int blk  = blockIdx.x;
    const int n    = blk / (NQB * S);
    const int rem  = blk % (NQB * S);
    const int qbi  = rem / S;
    const int s    = rem % S;
    const int qb   = qbi * QBLK;
    const int tid  = threadIdx.x;
    const int wave = tid >> 6;     // 0..3
    const int lane = tid & 63;
    const int lhi  = lane >> 4;    // 0..3
    const int llo  = lane & 15;    // q-row i within sub-tile

    const int jb_beg = s * TILES_PER * KVBLK;
    const int jb_end = min(L_, jb_beg + TILES_PER * KVBLK);

    const unsigned short* qtb = q_t + (size_t)n * L_ * CR_;
    const unsigned short* ktb = k_t + (size_t)n * L_ * CR_;
    const unsigned short* vb  = v   + (size_t)n * C_ * L_;

    // Q B-fragments (col=llo -> q-row, k=lhi*8+e -> c), 2 sub-tiles of 16 rows
    bf16x8 qf[2][2];
    #pragma unroll
    for (int st = 0; st < 2; st++) {
        int row = qb + wave * 32 + st * 16 + llo;
        #pragma unroll
        for (int ks = 0; ks < 2; ks++)
            qf[st][ks] = *reinterpret_cast<const bf16x8*>(qtb + (size_t)row * CR_ + ks*32 + lhi*8);
    }

    // staging sources (pre-swizzled global, linear LDS dest; 6 GLD16/thread)
    const int l8 = lane >> 3;          // 0..7
    const int l7 = (lane & 7) * 16;    // byte chunk within 128B row
    const int rho0 = wave*16 + l8;
    const int rho1 = rho0 + 8;
    const unsigned short* kbase0 = ktb + (size_t)sigma_(rho0) * CR_ + ((l7 ^ ((rho0 & 7) << 4)) >> 1);
    const unsigned short* kbase1 = ktb + (size_t)sigma_(rho1) * CR_ + ((l7 ^ ((rho1 & 7) << 4)) >> 1);
    const unsigned short* vbase[4];
    #pragma unroll
    for (int vt = 0; vt < 4; vt++) {
        int c = wave*32 + vt*8 + l8;
        vbase[vt] = vb + (size_t)c * L_ + ((l7 ^ (l8 << 4)) >> 1);
    }

    #define STAGE(b, jb_) do {                                                   \
        GLD16(kbase0 + (size_t)(jb_) * CR_, &kv_lds[b][(wave*2+0)*1024 + 0]);    \
        GLD16(kbase1 + (size_t)(jb_) * CR_, &kv_lds[b][(wave*2+1)*1024 + 0]);    \
        GLD16(vbase[0] + (jb_), &kv_lds[b][8192 + (wave*4+0)*1024]);             \
        GLD16(vbase[1] + (jb_), &kv_lds[b][8192 + (wave*4+1)*1024]);             \
        GLD16(vbase[2] + (jb_), &kv_lds[b][8192 + (wave*4+2)*1024]);             \
        GLD16(vbase[3] + (jb_), &kv_lds[b][8192 + (wave*4+3)*1024]);             \
    } while (0)

    f32x4 o_acc[2][8];
    #pragma unroll
    for (int st = 0; st < 2; st++)
        #pragma unroll
        for (int ct = 0; ct < 8; ct++) o_acc[st][ct] = f32x4{0.f, 0.f, 0.f, 0.f};
    float l_run[2] = {0.f, 0.f};

    int cur = 0;
    STAGE(0, jb_beg);
    __syncthreads();

    for (int jb = jb_beg; jb < jb_end; jb += KVBLK) {
        if (jb + KVBLK < jb_end) STAGE(cur ^ 1, jb + KVBLK);

        const unsigned char* kbuf = &kv_lds[cur][0];
        const unsigned char* vbuf = &kv_lds[cur][8192];

        // ---- S^T = K . Q^T : sacc[st][jt][r] = S^T(lds-row jt*16+lhi*4+r, i=llo) ----
        f32x4 sacc[2][4];
        #pragma unroll
        for (int st = 0; st < 2; st++)
            #pragma unroll
            for (int jt = 0; jt < 4; jt++) sacc[st][jt] = f32x4{0.f, 0.f, 0.f, 0.f};
        __builtin_amdgcn_s_setprio(1);
        #pragma unroll
        for (int ks = 0; ks < 2; ks++) {
            #pragma unroll
            for (int jt = 0; jt < 4; jt++) {
                int rho  = jt*16 + llo;
                int colb = ks*64 + lhi*16;
                bf16x8 kf = *reinterpret_cast<const bf16x8*>(
                    kbuf + rho*128 + (colb ^ ((rho & 7) << 4)));
                sacc[0][jt] = __builtin_amdgcn_mfma_f32_16x16x32_bf16(kf, qf[0][ks], sacc[0][jt], 0, 0, 0);
                sacc[1][jt] = __builtin_amdgcn_mfma_f32_16x16x32_bf16(kf, qf[1][ks], sacc[1][jt], 0, 0, 0);
            }
        }
        __builtin_amdgcn_s_setprio(0);

        // ---- P = exp2(S) directly (fixed shift m=0); per-lane l accumulate ----
        unsigned pk[2][8];
        #pragma unroll
        for (int st = 0; st < 2; st++) {
            float rs = 0.f;
            #pragma unroll
            for (int jt = 0; jt < 4; jt++) {
                float pa = exp2_fast(sacc[st][jt][0]);
                float pb = exp2_fast(sacc[st][jt][1]);
                float pc = exp2_fast(sacc[st][jt][2]);
                float pd = exp2_fast(sacc[st][jt][3]);
                rs += (pa + pb) + (pc + pd);
                pk[st][jt*2 + 0] = cvt_pk_bf16(pa, pb);
                pk[st][jt*2 + 1] = cvt_pk_bf16(pc, pd);
            }
            l_run[st] += rs;
        }

        // ---- O^T += V^T . P^T : vf shared across both sub-tiles ----
        __builtin_amdgcn_s_setprio(1);
        #pragma unroll
        for (int ks = 0; ks < 2; ks++) {
            bf16x8 pf0 = *reinterpret_cast<const bf16x8*>(&pk[0][4*ks]);
            bf16x8 pf1 = *reinterpret_cast<const bf16x8*>(&pk[1][4*ks]);
            #pragma unroll
            for (int ct = 0; ct < 8; ct++) {
                int c = ct*16 + llo;
                int colb = ks*64 + lhi*16;
                bf16x8 vf = *reinterpret_cast<const bf16x8*>(
                    vbuf + c*128 + (colb ^ ((c & 7) << 4)));
                o_acc[0][ct] = __builtin_amdgcn_mfma_f32_16x16x32_bf16(vf, pf0, o_acc[0][ct], 0, 0, 0);
                o_acc[1][ct] = __builtin_amdgcn_mfma_f32_16x16x32_bf16(vf, pf1, o_acc[1][ct], 0, 0, 0);
            }
        }
        __builtin_amdgcn_s_setprio(0);

        __syncthreads();   // drains prefetch (implicit vmcnt(0)) + buffer handoff
        cur ^= 1;
    }

    // ---- deferred cross-lane l reduce (once) ----
    #pragma unroll
    for (int st = 0; st < 2; st++) {
        l_run[st] += __shfl_xor(l_run[st], 16, 64);
        l_run[st] += __shfl_xor(l_run[st], 32, 64);
    }

    // ---- write partials: o_acc[st][ct][r] = O[c=ct*16+lhi*4+r][i=wave*32+st*16+llo]
    unsigned short* ob = o_part + ((size_t)(n*NQB + qbi)*S + s) * (QBLK*C_);
    float* lb = l_part + ((size_t)(n*NQB + qbi)*S + s) * QBLK;
    #pragma unroll
    for (int st = 0; st < 2; st++) {
        int i_loc = wave*32 + st*16 + llo;
        #pragma unroll
        for (int ct = 0; ct < 8; ct++) {
            int c0 = ct*16 + lhi*4;
            uint2 pkd;
            pkd.x = cvt_pk_bf16(o_acc[st][ct][0], o_acc[st][ct][1]);
            pkd.y = cvt_pk_bf16(o_acc[st][ct][2], o_acc[st][ct][3]);
            *reinterpret_cast<uint2*>(ob + (size_t)i_loc * C_ + c0) = pkd;
        }
        if (lhi == 0) {
            lb[i_loc] = l_run[st];
        }
    }
    #undef STAGE
}

// ---------------------------------------------------------------------------
// Combine: out[n][c][i] = (sum_s O_s[i][c]) / (sum_s l_s[i]) + x[n][c][i]
// Block = (n, q-tile, i-chunk of 32). 256 threads: (i=tid>>3, c-group=tid&7).
// ---------------------------------------------------------------------------
__global__ __launch_bounds__(256) void combine_kernel(
    const unsigned short* __restrict__ o_part,
    const float* __restrict__ l_part,
    const float* __restrict__ x,
    float* __restrict__ out,
    int S)
{
    __shared__ float invl[32];

    const int blk  = blockIdx.x;
    const int part = blk & 3;
    const int qbi  = (blk >> 2) % NQB;
    const int n    = blk / (4 * NQB);
    const int tid  = threadIdx.x;
    const int i0   = part * 32;

    const size_t pbase = (size_t)(n*NQB + qbi) * S;

    if (tid < 32) {
        float lt = 0.f;
        for (int s = 0; s < S; s++)
            lt += l_part[(pbase + s) * QBLK + i0 + tid];
        invl[tid] = 1.0f / lt;
    }
    __syncthreads();

    const int il = tid >> 3;           // 0..31
    const int cg = tid & 7;            // c-group: c = cg*16 .. +15

    float acc[16];
    #pragma unroll
    for (int k = 0; k < 16; k++) acc[k] = 0.f;

    for (int s = 0; s < S; s++) {
        const unsigned short* src = o_part + (pbase + s) * (QBLK*C_) + (size_t)(i0 + il) * C_ + cg*16;
        bf16x8 v0 = *reinterpret_cast<const bf16x8*>(src);
        bf16x8 v1 = *reinterpret_cast<const bf16x8*>(src + 8);
        #pragma unroll
        for (int k = 0; k < 8; k++) acc[k]     += bf2f((unsigned short)v0[k]);
        #pragma unroll
        for (int k = 0; k < 8; k++) acc[8 + k] += bf2f((unsigned short)v1[k]);
    }

    const float nv = invl[il];
    const int ig = qbi*QBLK + i0 + il;
    const float* xb = x   + (size_t)n * C_ * L_;
    float*       ob = out + (size_t)n * C_ * L_;
    #pragma unroll
    for (int k = 0; k < 16; k++) {
        int c = cg*16 + k;
        ob[(size_t)c * L_ + ig] = acc[k] * nv + xb[(size_t)c * L_ + ig];
    }
}

extern "C" void kernel_launch(void* const* d_in, const int* in_sizes, int n_in,
                              void* d_out, int out_size, void* d_ws, size_t ws_size,
                              hipStream_t stream) {
    const float* x  = (const float*)d_in[0];
    const float* w1 = (const float*)d_in[1];
    const float* b1 = (const float*)d_in[2];
    const float* a1 = (const float*)d_in[3];
    const float* w2 = (const float*)d_in[4];
    const float* b2 = (const float*)d_in[5];
    const float* a2 = (const float*)d_in[6];
    const float* wa = (const float*)d_in[7];
    const float* ba = (const float*)d_in[8];
    const float* aa = (const float*)d_in[9];
    float* out = (float*)d_out;

    unsigned short* qkv = (unsigned short*)d_ws;
    size_t qkv_bytes = ((size_t)2*N_*L_*CR_ + (size_t)N_*C_*L_) * 2;
    size_t off = (qkv_bytes + 255) & ~(size_t)255;

    // largest S<=8 fitting in ws (deterministic: ws_size fixed)
    int S = SMAX;
    while (S > 1) {
        size_t need = off + (size_t)N_*NQB*S * ((size_t)QBLK*C_*2 + QBLK*4);
        if (need <= ws_size) break;
        S--;
    }
    unsigned short* o_part = (unsigned short*)((char*)d_ws + off);
    size_t o_elems = (size_t)N_*NQB*S*QBLK*C_;
    float* l_part = (float*)(o_part + o_elems);
    int tiles_per = (L_/KVBLK + S - 1) / S;

    proj_kernel<<<N_ * (L_/32), 256, 0, stream>>>(x, w1, b1, a1, w2, b2, a2, wa, ba, aa, qkv);
    attn_kernel<<<N_ * NQB * S, 256, 0, stream>>>(qkv, o_part, l_part, S, tiles_per);
    combine_kernel<<<N_ * NQB * 4, 256, 0, stream>>>(o_part, l_part, x, out, S);
}